// Round 12
// baseline (144.472 us; speedup 1.0000x reference)
//
#include <hip/hip_runtime.h>

#define B_    4
#define TE_   256
#define TD_   256
#define DE_   512
#define K_    512

typedef __attribute__((ext_vector_type(8))) short bf16x8;
typedef __attribute__((ext_vector_type(4))) float f32x4;

// 2*log2(e): folded into Ua/Wa so the sigmoid arg is exp2-ready.
#define C1F 2.8853900817779268f

__device__ __forceinline__ ushort f2bf(float x) {
  uint u = __float_as_uint(x);
  return (ushort)((u + 0x7fffu + ((u >> 16) & 1u)) >> 16);
}
__device__ __forceinline__ float bf2f(ushort h) {
  return __uint_as_float(((uint)h) << 16);
}
__device__ __forceinline__ float exp2_fast(float x) {
  float r;
  asm("v_exp_f32 %0, %1" : "=v"(r) : "v"(x));
  return r;
}

// ---- one conversion kernel, 4 z-slices ----
// z=0/1: enc/dec [1024,512] f32 -> hi/lo bf16 row-major (512 blocks each)
// z=2/3: C1*Ua / C1*Wa [K,N] -> n-major [N,K] hi/lo bf16 (64 blocks each)
__global__ __launch_bounds__(256) void conv_all(
    const float* __restrict__ enc, const float* __restrict__ dec,
    const float* __restrict__ Ua, const float* __restrict__ Wa,
    ushort* __restrict__ ehi, ushort* __restrict__ elo,
    ushort* __restrict__ dhi, ushort* __restrict__ dlo,
    ushort* __restrict__ uhi, ushort* __restrict__ ulo,
    ushort* __restrict__ whi, ushort* __restrict__ wlo) {
  int z = blockIdx.z, tid = threadIdx.x;
  if (z < 2) {
    const float* in = z ? dec : enc;
    ushort* hi = z ? dhi : ehi;
    ushort* lo = z ? dlo : elo;
    int i = (blockIdx.x * 256 + tid) * 4;
    float4 v = *(const float4*)&in[i];
    ushort4 h, l;
    h.x = f2bf(v.x); l.x = f2bf(v.x - bf2f(h.x));
    h.y = f2bf(v.y); l.y = f2bf(v.y - bf2f(h.y));
    h.z = f2bf(v.z); l.z = f2bf(v.z - bf2f(h.z));
    h.w = f2bf(v.w); l.w = f2bf(v.w - bf2f(h.w));
    *(ushort4*)&hi[i] = h;
    *(ushort4*)&lo[i] = l;
    return;
  }
  if (blockIdx.x >= 64) return;
  const float* in = (z == 3) ? Wa : Ua;
  ushort* thi = (z == 3) ? whi : uhi;
  ushort* tlo = (z == 3) ? wlo : ulo;
  __shared__ float tile[64][65];
  int k0 = (blockIdx.x >> 3) * 64, n0 = (blockIdx.x & 7) * 64;
#pragma unroll
  for (int i = 0; i < 16; ++i) {
    int idx = tid + i * 256;
    int r = idx >> 6, c = idx & 63;
    tile[r][c] = in[(size_t)(k0 + r) * 512 + n0 + c];
  }
  __syncthreads();
#pragma unroll
  for (int i = 0; i < 16; ++i) {
    int idx = tid + i * 256;
    int rn = idx >> 6, ck = idx & 63;
    float x = tile[ck][rn] * C1F;
    ushort h = f2bf(x);
    size_t o = (size_t)(n0 + rn) * 512 + k0 + ck;
    thi[o] = h;
    tlo[o] = f2bf(x - bf2f(h));
  }
}

// ---- LDS-free split-bf16 MFMA GEMM: 16x16 tiles, 4 indep waves/block ----
// 4096 tiles -> 4096 waves (4/SIMD). Frags gathered straight from global.
// z=0: UhT[d][b*256+e] = (C1*Ua)^T @ enc^T   (A=uhi, B=ehi)
// z=1: Ws[b*256+t][d]  = dec @ (C1*Wa)       (A=dhi, B=whi)
// 3-term split: hh + hl + lh.
__global__ __launch_bounds__(256, 4) void gemm_mfma(
    const ushort* __restrict__ ehi, const ushort* __restrict__ elo,
    const ushort* __restrict__ dhi, const ushort* __restrict__ dlo,
    const ushort* __restrict__ uhi, const ushort* __restrict__ ulo,
    const ushort* __restrict__ whi, const ushort* __restrict__ wlo,
    float* __restrict__ UhT, float* __restrict__ Ws) {
  const ushort *Ahi, *Alo, *Bhi, *Blo;
  int tid = threadIdx.x, lane = tid & 63;
  int ti = blockIdx.x * 4 + (tid >> 6);           // global tile id
  int bm, bn;
  if (blockIdx.z == 0) {
    Ahi = uhi; Alo = ulo; Bhi = ehi; Blo = elo;   // M=512(d), N=1024(b,e)
    bm = (ti >> 6) * 16; bn = (ti & 63) * 16;
  } else {
    Ahi = dhi; Alo = dlo; Bhi = whi; Blo = wlo;   // M=1024(b,t), N=512(d)
    bm = (ti >> 5) * 16; bn = (ti & 31) * 16;
  }
  int frow = lane & 15, fk = (lane >> 4) * 8;     // frag row, 16B k-chunk
  size_t ao = (size_t)(bm + frow) * K_ + fk;
  size_t bo = (size_t)(bn + frow) * K_ + fk;
  const ushort* pah = Ahi + ao;
  const ushort* pal = Alo + ao;
  const ushort* pbh = Bhi + bo;
  const ushort* pbl = Blo + bo;
  f32x4 acc = {};
#pragma unroll 4
  for (int k0 = 0; k0 < K_; k0 += 32) {
    bf16x8 ah = *(const bf16x8*)&pah[k0];
    bf16x8 al = *(const bf16x8*)&pal[k0];
    bf16x8 bh = *(const bf16x8*)&pbh[k0];
    bf16x8 bl = *(const bf16x8*)&pbl[k0];
    acc = __builtin_amdgcn_mfma_f32_16x16x32_bf16(ah, bh, acc, 0, 0, 0);
    acc = __builtin_amdgcn_mfma_f32_16x16x32_bf16(ah, bl, acc, 0, 0, 0);
    acc = __builtin_amdgcn_mfma_f32_16x16x32_bf16(al, bh, acc, 0, 0, 0);
  }
  // C/D: col=lane&15, row=(lane>>4)*4+r  [verified empirically r6]
  int m0 = bm + (lane >> 4) * 4;
  int n0 = bn + (lane & 15);
  if (blockIdx.z == 0) {
    float* cb = UhT + (size_t)(n0 >> 8) * 131072 + (size_t)m0 * 256 + (n0 & 255);
#pragma unroll
    for (int r = 0; r < 4; ++r) cb[(size_t)r * 256] = acc[r];
  } else {
    float* cb = Ws + (size_t)m0 * 512 + n0;
#pragma unroll
    for (int r = 0; r < 4; ++r) cb[(size_t)r * 512] = acc[r];
  }
}

// ---- fused energies + softmax + context ----
// 512 blocks x 1024 thr (16 waves) -> 2 blocks/CU = 32 waves/CU (100% cap).
// Phase 1: wave w owns d in [w*32, w*32+32); per d-row the wave loads
// UhT[b][d][0..255] (1KB contiguous, 64 lanes x float4); lane evals 8
// sigmoids (4e x 2t). Cross-wave reduce via part[32][260].
// Energy: e~ = sum mv[d]*rcp(1+2^(u'+w')), mv=-2*Va (softmax-invariant).
__global__ __launch_bounds__(1024, 8) void fused_attn(
    const float* __restrict__ enc, const float* __restrict__ UhT,
    const float* __restrict__ Ws, const float* __restrict__ Va,
    float* __restrict__ out_ctx, float* __restrict__ out_attn) {
  int bt = blockIdx.x;
  int b  = bt >> 7;
  int t0 = (bt & 127) * 2;
  __shared__ float ws0_s[520], ws1_s[520], mv_s[520];   // pad: idx d+(d>>6)
  __shared__ float part[32][260];                       // [w*2+t][e]
  __shared__ float att2[TE_ * 2];                       // [e][t]
  __shared__ float redm[2][4], reds[2][4];
  int tid = threadIdx.x, lane = tid & 63, w = tid >> 6;  // w in [0,16)

  if (tid < 512) {
    const float* wsr = Ws + (size_t)(b * TD_ + t0) * DE_;
    int pd = tid + (tid >> 6);
    ws0_s[pd] = wsr[tid];
    ws1_s[pd] = wsr[DE_ + tid];
    mv_s[pd]  = -2.0f * Va[tid];
  }
  __syncthreads();

  // ---- phase 1: wave-coalesced d-row sweep ----
  const float* up = UhT + (size_t)b * 131072 + (size_t)w * 32 * 256 + lane * 4;
  float a0[4] = {}, a1[4] = {};
#pragma unroll 4
  for (int row = 0; row < 32; ++row) {
    float4 u4 = *(const float4*)&up[row * 256];
    int d = w * 32 + row, pd = d + (d >> 6);
    float w0 = ws0_s[pd], w1 = ws1_s[pd], mv = mv_s[pd];
#pragma unroll
    for (int j = 0; j < 4; ++j) {
      float u = j == 0 ? u4.x : j == 1 ? u4.y : j == 2 ? u4.z : u4.w;
      a0[j] = fmaf(mv, __builtin_amdgcn_rcpf(1.0f + exp2_fast(u + w0)), a0[j]);
      a1[j] = fmaf(mv, __builtin_amdgcn_rcpf(1.0f + exp2_fast(u + w1)), a1[j]);
    }
  }
  *(float4*)&part[w * 2 + 0][lane * 4] = make_float4(a0[0], a0[1], a0[2], a0[3]);
  *(float4*)&part[w * 2 + 1][lane * 4] = make_float4(a1[0], a1[1], a1[2], a1[3]);
  __syncthreads();

  // ---- phase 2: 16-way reduce + softmax (threads 0-511; t=tid>>8) ----
  int t = tid >> 8, col = tid & 255;
  float x = 0.f, p = 0.f, m, s;
  if (tid < 512) {
#pragma unroll
    for (int ww = 0; ww < 16; ++ww) x += part[ww * 2 + t][col];
    m = x;
#pragma unroll
    for (int off = 32; off; off >>= 1) m = fmaxf(m, __shfl_xor(m, off));
    if (lane == 0) redm[t][w & 3] = m;
  }
  __syncthreads();
  if (tid < 512) {
    m = fmaxf(fmaxf(redm[t][0], redm[t][1]), fmaxf(redm[t][2], redm[t][3]));
    p = __expf(x - m);
    s = p;
#pragma unroll
    for (int off = 32; off; off >>= 1) s += __shfl_xor(s, off);
    if (lane == 0) reds[t][w & 3] = s;
  }
  __syncthreads();
  if (tid < 512) {
    s = reds[t][0] + reds[t][1] + reds[t][2] + reds[t][3];
    float a = p * __builtin_amdgcn_rcpf(s);
    att2[col * 2 + t] = a;
    out_attn[(size_t)(b * TD_ + t0 + t) * TE_ + col] = a;
  }
  __syncthreads();

  // ---- phase 3: context; thread owns (d = tid&511, t = tid>>9) ----
  int d = tid & 511, tt = tid >> 9;
  const float* enc_b = enc + (size_t)b * TE_ * DE_;
  float c = 0.f;
#pragma unroll 4
  for (int ee = 0; ee < TE_; ++ee)
    c = fmaf(att2[ee * 2 + tt], enc_b[(size_t)ee * DE_ + d], c);
  out_ctx[(size_t)(b * TD_ + t0 + tt) * DE_ + d] = c;
}

extern "C" void kernel_launch(void* const* d_in, const int* in_sizes, int n_in,
                              void* d_out, int out_size, void* d_ws, size_t ws_size,
                              hipStream_t stream) {
  const float* enc = (const float*)d_in[0];
  const float* dec = (const float*)d_in[1];
  const float* Ua  = (const float*)d_in[2];
  const float* Wa  = (const float*)d_in[3];
  const float* Va  = (const float*)d_in[4];

  float* out_ctx  = (float*)d_out;                     // [B,TD,DE]
  float* out_attn = out_ctx + (size_t)B_ * TD_ * DE_;  // [B,TD,TE]

  char* wsp = (char*)d_ws;
  float* UhT = (float*)wsp;             wsp += (size_t)B_ * DE_ * TE_ * 4;  // [B][512 d][256 e]
  float* Wsm = (float*)wsp;             wsp += (size_t)B_ * TD_ * DE_ * 4;  // [B*256 t][512 d]
  ushort* ehi = (ushort*)wsp;           wsp += (size_t)B_ * TE_ * DE_ * 2;
  ushort* elo = (ushort*)wsp;           wsp += (size_t)B_ * TE_ * DE_ * 2;
  ushort* dhi = (ushort*)wsp;           wsp += (size_t)B_ * TD_ * DE_ * 2;
  ushort* dlo = (ushort*)wsp;           wsp += (size_t)B_ * TD_ * DE_ * 2;
  ushort* uhi = (ushort*)wsp;           wsp += (size_t)K_ * DE_ * 2;
  ushort* ulo = (ushort*)wsp;           wsp += (size_t)K_ * DE_ * 2;
  ushort* whi = (ushort*)wsp;           wsp += (size_t)K_ * DE_ * 2;
  ushort* wlo = (ushort*)wsp;           wsp += (size_t)K_ * DE_ * 2;

  conv_all<<<dim3(512, 1, 4), 256, 0, stream>>>(
      enc, dec, Ua, Wa, ehi, elo, dhi, dlo, uhi, ulo, whi, wlo);
  gemm_mfma<<<dim3(512, 1, 2), 256, 0, stream>>>(
      ehi, elo, dhi, dlo, uhi, ulo, whi, wlo, UhT, Wsm);
  fused_attn<<<512, 1024, 0, stream>>>(enc, UhT, Wsm, Va, out_ctx, out_attn);
}

// Round 13
// 123.453 us; speedup vs baseline: 1.1703x; 1.1703x over previous
//
#include <hip/hip_runtime.h>

#define B_    4
#define TE_   256
#define TD_   256
#define DE_   512
#define K_    512

typedef __attribute__((ext_vector_type(8))) short bf16x8;
typedef __attribute__((ext_vector_type(4))) float f32x4;

// 2*log2(e): folded into Ua/Wa so the sigmoid arg is exp2-ready.
#define C1F 2.8853900817779268f

__device__ __forceinline__ ushort f2bf(float x) {
  uint u = __float_as_uint(x);
  return (ushort)((u + 0x7fffu + ((u >> 16) & 1u)) >> 16);
}
__device__ __forceinline__ float bf2f(ushort h) {
  return __uint_as_float(((uint)h) << 16);
}
__device__ __forceinline__ float exp2_fast(float x) {
  float r;
  asm("v_exp_f32 %0, %1" : "=v"(r) : "v"(x));
  return r;
}

// ---- enc/dec [1024,512] f32 -> hi/lo bf16 (row-major) ----
__global__ __launch_bounds__(256) void conv_hilo(
    const float* __restrict__ enc, const float* __restrict__ dec,
    ushort* __restrict__ ehi, ushort* __restrict__ elo,
    ushort* __restrict__ dhi, ushort* __restrict__ dlo) {
  const float* in = blockIdx.y ? dec : enc;
  ushort* hi = blockIdx.y ? dhi : ehi;
  ushort* lo = blockIdx.y ? dlo : elo;
  int i = (blockIdx.x * 256 + threadIdx.x) * 4;
  float4 v = *(const float4*)&in[i];
  ushort4 h, l;
  h.x = f2bf(v.x); l.x = f2bf(v.x - bf2f(h.x));
  h.y = f2bf(v.y); l.y = f2bf(v.y - bf2f(h.y));
  h.z = f2bf(v.z); l.z = f2bf(v.z - bf2f(h.z));
  h.w = f2bf(v.w); l.w = f2bf(v.w - bf2f(h.w));
  *(ushort4*)&hi[i] = h;
  *(ushort4*)&lo[i] = l;
}

// ---- C1*Ua, C1*Wa [K,N] -> n-major [N,K] hi/lo bf16 ----
__global__ __launch_bounds__(256) void conv_bt(
    const float* __restrict__ Ua, const float* __restrict__ Wa,
    ushort* __restrict__ uhi, ushort* __restrict__ ulo,
    ushort* __restrict__ whi, ushort* __restrict__ wlo) {
  const float* in = blockIdx.z ? Wa : Ua;
  ushort* thi = blockIdx.z ? whi : uhi;
  ushort* tlo = blockIdx.z ? wlo : ulo;
  __shared__ float tile[64][65];
  int k0 = blockIdx.y * 64, n0 = blockIdx.x * 64;
  int tid = threadIdx.x;
#pragma unroll
  for (int i = 0; i < 16; ++i) {
    int idx = tid + i * 256;
    int r = idx >> 6, c = idx & 63;
    tile[r][c] = in[(size_t)(k0 + r) * 512 + n0 + c];
  }
  __syncthreads();
#pragma unroll
  for (int i = 0; i < 16; ++i) {
    int idx = tid + i * 256;
    int rn = idx >> 6, ck = idx & 63;
    float x = tile[ck][rn] * C1F;
    ushort h = f2bf(x);
    size_t o = (size_t)(n0 + rn) * 512 + k0 + ck;
    thi[o] = h;
    tlo[o] = f2bf(x - bf2f(h));
  }
}

// ---- LDS-free split-bf16 MFMA GEMM, 16x32 double-tile per wave ----
// 2048 waves (2/SIMD). A-frag reused across 2 B-tiles. Epilogue: E = 2^acc
// (exp-split: fused kernel multiplies E_u*E_w instead of exp2(u+w)).
// z=0: EuT[d][b*256+e] = 2^((C1*Ua)^T @ enc^T)   (A=uhi, B=ehi)
// z=1: Ew[b*256+t][d]  = 2^(dec @ (C1*Wa))       (A=dhi, B=whi)
// 3-term split: hh + hl + lh.
__global__ __launch_bounds__(256, 4) void gemm_mfma(
    const ushort* __restrict__ ehi, const ushort* __restrict__ elo,
    const ushort* __restrict__ dhi, const ushort* __restrict__ dlo,
    const ushort* __restrict__ uhi, const ushort* __restrict__ ulo,
    const ushort* __restrict__ whi, const ushort* __restrict__ wlo,
    float* __restrict__ EuT, float* __restrict__ Ew) {
  const ushort *Ahi, *Alo, *Bhi, *Blo;
  int tid = threadIdx.x, lane = tid & 63;
  int ti = blockIdx.x * 4 + (tid >> 6);           // global double-tile id
  int bm, bn;
  if (blockIdx.z == 0) {
    Ahi = uhi; Alo = ulo; Bhi = ehi; Blo = elo;   // M=512(d), N=1024(b,e)
    bm = (ti >> 5) * 16; bn = (ti & 31) * 32;
  } else {
    Ahi = dhi; Alo = dlo; Bhi = whi; Blo = wlo;   // M=1024(b,t), N=512(d)
    bm = (ti >> 4) * 16; bn = (ti & 15) * 32;
  }
  int frow = lane & 15, fk = (lane >> 4) * 8;     // frag row, 16B k-chunk
  size_t ao = (size_t)(bm + frow) * K_ + fk;
  size_t bo = (size_t)(bn + frow) * K_ + fk;
  const ushort* pah = Ahi + ao;
  const ushort* pal = Alo + ao;
  const ushort* pbh0 = Bhi + bo; const ushort* pbh1 = pbh0 + 16 * K_;
  const ushort* pbl0 = Blo + bo; const ushort* pbl1 = pbl0 + 16 * K_;
  f32x4 acc0 = {}, acc1 = {};
#pragma unroll 4
  for (int k0 = 0; k0 < K_; k0 += 32) {
    bf16x8 ah = *(const bf16x8*)&pah[k0];
    bf16x8 al = *(const bf16x8*)&pal[k0];
    bf16x8 bh0 = *(const bf16x8*)&pbh0[k0];
    bf16x8 bl0 = *(const bf16x8*)&pbl0[k0];
    bf16x8 bh1 = *(const bf16x8*)&pbh1[k0];
    bf16x8 bl1 = *(const bf16x8*)&pbl1[k0];
    acc0 = __builtin_amdgcn_mfma_f32_16x16x32_bf16(ah, bh0, acc0, 0, 0, 0);
    acc1 = __builtin_amdgcn_mfma_f32_16x16x32_bf16(ah, bh1, acc1, 0, 0, 0);
    acc0 = __builtin_amdgcn_mfma_f32_16x16x32_bf16(ah, bl0, acc0, 0, 0, 0);
    acc1 = __builtin_amdgcn_mfma_f32_16x16x32_bf16(ah, bl1, acc1, 0, 0, 0);
    acc0 = __builtin_amdgcn_mfma_f32_16x16x32_bf16(al, bh0, acc0, 0, 0, 0);
    acc1 = __builtin_amdgcn_mfma_f32_16x16x32_bf16(al, bh1, acc1, 0, 0, 0);
  }
  // C/D: col=lane&15, row=(lane>>4)*4+r  [verified empirically r6]
  int m0 = bm + (lane >> 4) * 4;
#pragma unroll
  for (int j = 0; j < 2; ++j) {
    const f32x4& acc = j ? acc1 : acc0;
    int n0 = bn + j * 16 + (lane & 15);
    if (blockIdx.z == 0) {
      float* cb = EuT + (size_t)(n0 >> 8) * 131072 + (size_t)m0 * 256 + (n0 & 255);
#pragma unroll
      for (int r = 0; r < 4; ++r) cb[(size_t)r * 256] = exp2_fast(acc[r]);
    } else {
      float* cb = Ew + (size_t)m0 * 512 + n0;
#pragma unroll
      for (int r = 0; r < 4; ++r) cb[(size_t)r * 512] = exp2_fast(acc[r]);
    }
  }
}

// ---- fused energies + softmax + context ----
// 512 blocks x 1024 thr (16 waves). Phase 1: wave w owns d in [w*32,w*32+32);
// per d-row the wave loads EuT[b][d][0..255] (1KB contiguous); inner element:
// acc += mv * rcp(fma(eu, ew, 1)) -- 3 insts, 1 trans (exp-split).
// Energy: e~ = sum mv[d]*sigmoid-term, mv=-2*Va (softmax-invariant shift).
__global__ __launch_bounds__(1024, 8) void fused_attn(
    const float* __restrict__ enc, const float* __restrict__ EuT,
    const float* __restrict__ Ew, const float* __restrict__ Va,
    float* __restrict__ out_ctx, float* __restrict__ out_attn) {
  int bt = blockIdx.x;
  int b  = bt >> 7;
  int t0 = (bt & 127) * 2;
  __shared__ float ew0_s[520], ew1_s[520], mv_s[520];   // pad: idx d+(d>>6)
  __shared__ float part[32][260];                       // [w*2+t][e]
  __shared__ float att2[TE_ * 2];                       // [e][t]
  __shared__ float ctxp[2][2][512];                     // [e-half][t][d]
  __shared__ float redm[2][4], reds[2][4];
  int tid = threadIdx.x, lane = tid & 63, w = tid >> 6;  // w in [0,16)

  if (tid < 512) {
    const float* ewr = Ew + (size_t)(b * TD_ + t0) * DE_;
    int pd = tid + (tid >> 6);
    ew0_s[pd] = ewr[tid];
    ew1_s[pd] = ewr[DE_ + tid];
    mv_s[pd]  = -2.0f * Va[tid];
  }
  __syncthreads();

  // ---- phase 1: wave-coalesced d-row sweep ----
  const float* up = EuT + (size_t)b * 131072 + (size_t)w * 32 * 256 + lane * 4;
  float a0[4] = {}, a1[4] = {};
#pragma unroll 4
  for (int row = 0; row < 32; ++row) {
    float4 u4 = *(const float4*)&up[row * 256];
    int d = w * 32 + row, pd = d + (d >> 6);
    float e0 = ew0_s[pd], e1 = ew1_s[pd], mv = mv_s[pd];
#pragma unroll
    for (int j = 0; j < 4; ++j) {
      float u = j == 0 ? u4.x : j == 1 ? u4.y : j == 2 ? u4.z : u4.w;
      a0[j] = fmaf(mv, __builtin_amdgcn_rcpf(fmaf(u, e0, 1.0f)), a0[j]);
      a1[j] = fmaf(mv, __builtin_amdgcn_rcpf(fmaf(u, e1, 1.0f)), a1[j]);
    }
  }
  *(float4*)&part[w * 2 + 0][lane * 4] = make_float4(a0[0], a0[1], a0[2], a0[3]);
  *(float4*)&part[w * 2 + 1][lane * 4] = make_float4(a1[0], a1[1], a1[2], a1[3]);
  __syncthreads();

  // ---- phase 2: 16-way reduce + softmax (threads 0-511; t=tid>>8) ----
  int t = tid >> 8, col = tid & 255;
  float x = 0.f, p = 0.f, m, s;
  if (tid < 512) {
#pragma unroll
    for (int ww = 0; ww < 16; ++ww) x += part[ww * 2 + t][col];
    m = x;
#pragma unroll
    for (int off = 32; off; off >>= 1) m = fmaxf(m, __shfl_xor(m, off));
    if (lane == 0) redm[t][w & 3] = m;
  }
  __syncthreads();
  if (tid < 512) {
    m = fmaxf(fmaxf(redm[t][0], redm[t][1]), fmaxf(redm[t][2], redm[t][3]));
    p = __expf(x - m);
    s = p;
#pragma unroll
    for (int off = 32; off; off >>= 1) s += __shfl_xor(s, off);
    if (lane == 0) reds[t][w & 3] = s;
  }
  __syncthreads();
  if (tid < 512) {
    s = reds[t][0] + reds[t][1] + reds[t][2] + reds[t][3];
    float a = p * __builtin_amdgcn_rcpf(s);
    att2[col * 2 + t] = a;
    out_attn[(size_t)(b * TD_ + t0 + t) * TE_ + col] = a;
  }
  __syncthreads();

  // ---- phase 3: context; thread owns (d = tid&511, e-half = tid>>9),
  //      accumulates BOTH t rows over its 128-e half; LDS combine. ----
  int d = tid & 511, half = tid >> 9;
  const float* enc_b = enc + (size_t)b * TE_ * DE_ + (size_t)half * 128 * DE_;
  float c0 = 0.f, c1 = 0.f;
#pragma unroll 4
  for (int ee = 0; ee < 128; ++ee) {
    float2 av = *(const float2*)&att2[(half * 128 + ee) * 2];
    float xv = enc_b[(size_t)ee * DE_ + d];
    c0 = fmaf(av.x, xv, c0);
    c1 = fmaf(av.y, xv, c1);
  }
  ctxp[half][0][d] = c0;
  ctxp[half][1][d] = c1;
  __syncthreads();
  int tt = tid >> 9, dd = tid & 511;
  out_ctx[(size_t)(b * TD_ + t0 + tt) * DE_ + dd] =
      ctxp[0][tt][dd] + ctxp[1][tt][dd];
}

extern "C" void kernel_launch(void* const* d_in, const int* in_sizes, int n_in,
                              void* d_out, int out_size, void* d_ws, size_t ws_size,
                              hipStream_t stream) {
  const float* enc = (const float*)d_in[0];
  const float* dec = (const float*)d_in[1];
  const float* Ua  = (const float*)d_in[2];
  const float* Wa  = (const float*)d_in[3];
  const float* Va  = (const float*)d_in[4];

  float* out_ctx  = (float*)d_out;                     // [B,TD,DE]
  float* out_attn = out_ctx + (size_t)B_ * TD_ * DE_;  // [B,TD,TE]

  char* wsp = (char*)d_ws;
  float* EuT = (float*)wsp;             wsp += (size_t)B_ * DE_ * TE_ * 4;  // [B][512 d][256 e]
  float* Ewm = (float*)wsp;             wsp += (size_t)B_ * TD_ * DE_ * 4;  // [B*256 t][512 d]
  ushort* ehi = (ushort*)wsp;           wsp += (size_t)B_ * TE_ * DE_ * 2;
  ushort* elo = (ushort*)wsp;           wsp += (size_t)B_ * TE_ * DE_ * 2;
  ushort* dhi = (ushort*)wsp;           wsp += (size_t)B_ * TD_ * DE_ * 2;
  ushort* dlo = (ushort*)wsp;           wsp += (size_t)B_ * TD_ * DE_ * 2;
  ushort* uhi = (ushort*)wsp;           wsp += (size_t)K_ * DE_ * 2;
  ushort* ulo = (ushort*)wsp;           wsp += (size_t)K_ * DE_ * 2;
  ushort* whi = (ushort*)wsp;           wsp += (size_t)K_ * DE_ * 2;
  ushort* wlo = (ushort*)wsp;           wsp += (size_t)K_ * DE_ * 2;

  conv_hilo<<<dim3(512, 2), 256, 0, stream>>>(enc, dec, ehi, elo, dhi, dlo);
  conv_bt<<<dim3(8, 8, 2), 256, 0, stream>>>(Ua, Wa, uhi, ulo, whi, wlo);
  gemm_mfma<<<dim3(256, 1, 2), 256, 0, stream>>>(
      ehi, elo, dhi, dlo, uhi, ulo, whi, wlo, EuT, Ewm);
  fused_attn<<<512, 1024, 0, stream>>>(enc, EuT, Ewm, Va, out_ctx, out_attn);
}

// Round 15
// 112.938 us; speedup vs baseline: 1.2792x; 1.0931x over previous
//
#include <hip/hip_runtime.h>

#define B_    4
#define TE_   256
#define TD_   256
#define DE_   512
#define K_    512

typedef __attribute__((ext_vector_type(8))) short bf16x8;
typedef __attribute__((ext_vector_type(4))) float f32x4;

// 2*log2(e): folded into Ua/Wa so the sigmoid arg is exp2-ready.
#define C1F 2.8853900817779268f

__device__ __forceinline__ ushort f2bf(float x) {
  uint u = __float_as_uint(x);
  return (ushort)((u + 0x7fffu + ((u >> 16) & 1u)) >> 16);
}
__device__ __forceinline__ float bf2f(ushort h) {
  return __uint_as_float(((uint)h) << 16);
}
__device__ __forceinline__ float exp2_fast(float x) {
  float r;
  asm("v_exp_f32 %0, %1" : "=v"(r) : "v"(x));
  return r;
}

struct HL { bf16x8 h, l; };

__device__ __forceinline__ HL mk_hl(const float* v) {
  HL r;
#pragma unroll
  for (int j = 0; j < 8; ++j) {
    ushort hh = f2bf(v[j]);
    r.h[j] = (short)hh;
    r.l[j] = (short)f2bf(v[j] - bf2f(hh));
  }
  return r;
}
// 8 consecutive f32 (row-major operand) -> hi/lo bf16x8
__device__ __forceinline__ HL cvt_row(const float* p) {
  float4 a = *(const float4*)p, b = *(const float4*)(p + 4);
  float v[8] = {a.x, a.y, a.z, a.w, b.x, b.y, b.z, b.w};
  return mk_hl(v);
}
// 8 stride-512 f32 (transposed operand), scaled by C1 -> hi/lo bf16x8
__device__ __forceinline__ HL cvt_col(const float* p) {
  float v[8];
#pragma unroll
  for (int j = 0; j < 8; ++j) v[j] = p[(size_t)j * 512] * C1F;
  return mk_hl(v);
}

// ---- fused convert+GEMM (split-bf16, 3-term hh+hl+lh), 16x32/wave ----
// Reads f32 sources directly; converts fragments in registers (no conv
// kernels, no bf16 intermediates). Epilogue writes E = 2^acc (exp-split).
// z=0: EuT[d][b*256+e] = 2^((C1*Ua)^T @ enc^T)
// z=1: Ew[b*256+t][d]  = 2^(dec @ (C1*Wa))
__global__ __launch_bounds__(256, 2) void gemm_conv(
    const float* __restrict__ enc, const float* __restrict__ dec,
    const float* __restrict__ Ua, const float* __restrict__ Wa,
    float* __restrict__ EuT, float* __restrict__ Ew) {
  int tid = threadIdx.x, lane = tid & 63;
  int ti = blockIdx.x * 4 + (tid >> 6);           // global double-tile id
  int frow = lane & 15, fk = (lane >> 4) * 8;     // frag row, 8-elem k-chunk
  f32x4 acc0 = {}, acc1 = {};
  int bm, bn;
  if (blockIdx.z == 0) {
    bm = (ti >> 5) * 16; bn = (ti & 31) * 32;     // M=512(d), N=1024(b,e)
    const float* pA  = Ua + (size_t)fk * 512 + bm + frow;       // col-gather
    const float* pB0 = enc + (size_t)(bn + frow) * 512 + fk;
    const float* pB1 = enc + (size_t)(bn + 16 + frow) * 512 + fk;
#pragma unroll 2
    for (int k0 = 0; k0 < K_; k0 += 32) {
      HL A  = cvt_col(pA + (size_t)k0 * 512);
      HL B0 = cvt_row(pB0 + k0);
      HL B1 = cvt_row(pB1 + k0);
      acc0 = __builtin_amdgcn_mfma_f32_16x16x32_bf16(A.h, B0.h, acc0, 0, 0, 0);
      acc1 = __builtin_amdgcn_mfma_f32_16x16x32_bf16(A.h, B1.h, acc1, 0, 0, 0);
      acc0 = __builtin_amdgcn_mfma_f32_16x16x32_bf16(A.h, B0.l, acc0, 0, 0, 0);
      acc1 = __builtin_amdgcn_mfma_f32_16x16x32_bf16(A.h, B1.l, acc1, 0, 0, 0);
      acc0 = __builtin_amdgcn_mfma_f32_16x16x32_bf16(A.l, B0.h, acc0, 0, 0, 0);
      acc1 = __builtin_amdgcn_mfma_f32_16x16x32_bf16(A.l, B1.h, acc1, 0, 0, 0);
    }
  } else {
    bm = (ti >> 4) * 16; bn = (ti & 15) * 32;     // M=1024(b,t), N=512(d)
    const float* pA  = dec + (size_t)(bm + frow) * 512 + fk;
    const float* pB0 = Wa + (size_t)fk * 512 + bn + frow;       // col-gather
    const float* pB1 = Wa + (size_t)fk * 512 + bn + 16 + frow;
#pragma unroll 2
    for (int k0 = 0; k0 < K_; k0 += 32) {
      HL A  = cvt_row(pA + k0);
      HL B0 = cvt_col(pB0 + (size_t)k0 * 512);
      HL B1 = cvt_col(pB1 + (size_t)k0 * 512);
      acc0 = __builtin_amdgcn_mfma_f32_16x16x32_bf16(A.h, B0.h, acc0, 0, 0, 0);
      acc1 = __builtin_amdgcn_mfma_f32_16x16x32_bf16(A.h, B1.h, acc1, 0, 0, 0);
      acc0 = __builtin_amdgcn_mfma_f32_16x16x32_bf16(A.h, B0.l, acc0, 0, 0, 0);
      acc1 = __builtin_amdgcn_mfma_f32_16x16x32_bf16(A.h, B1.l, acc1, 0, 0, 0);
      acc0 = __builtin_amdgcn_mfma_f32_16x16x32_bf16(A.l, B0.h, acc0, 0, 0, 0);
      acc1 = __builtin_amdgcn_mfma_f32_16x16x32_bf16(A.l, B1.h, acc1, 0, 0, 0);
    }
  }
  // C/D: col=lane&15, row=(lane>>4)*4+r  [verified empirically r6]
  int m0 = bm + (lane >> 4) * 4;
#pragma unroll
  for (int j = 0; j < 2; ++j) {
    const f32x4& acc = j ? acc1 : acc0;
    int n0 = bn + j * 16 + (lane & 15);
    if (blockIdx.z == 0) {
      float* cb = EuT + (size_t)(n0 >> 8) * 131072 + (size_t)m0 * 256 + (n0 & 255);
#pragma unroll
      for (int r = 0; r < 4; ++r) cb[(size_t)r * 256] = exp2_fast(acc[r]);
    } else {
      float* cb = Ew + (size_t)m0 * 512 + n0;
#pragma unroll
      for (int r = 0; r < 4; ++r) cb[(size_t)r * 512] = exp2_fast(acc[r]);
    }
  }
}

// ---- fused energies + softmax + context (unchanged from r13) ----
__global__ __launch_bounds__(1024, 8) void fused_attn(
    const float* __restrict__ enc, const float* __restrict__ EuT,
    const float* __restrict__ Ew, const float* __restrict__ Va,
    float* __restrict__ out_ctx, float* __restrict__ out_attn) {
  int bt = blockIdx.x;
  int b  = bt >> 7;
  int t0 = (bt & 127) * 2;
  __shared__ float ew0_s[520], ew1_s[520], mv_s[520];   // pad: idx d+(d>>6)
  __shared__ float part[32][260];                       // [w*2+t][e]
  __shared__ float att2[TE_ * 2];                       // [e][t]
  __shared__ float ctxp[2][2][512];                     // [e-half][t][d]
  __shared__ float redm[2][4], reds[2][4];
  int tid = threadIdx.x, lane = tid & 63, w = tid >> 6;  // w in [0,16)

  if (tid < 512) {
    const float* ewr = Ew + (size_t)(b * TD_ + t0) * DE_;
    int pd = tid + (tid >> 6);
    ew0_s[pd] = ewr[tid];
    ew1_s[pd] = ewr[DE_ + tid];
    mv_s[pd]  = -2.0f * Va[tid];
  }
  __syncthreads();

  // ---- phase 1: wave-coalesced d-row sweep ----
  const float* up = EuT + (size_t)b * 131072 + (size_t)w * 32 * 256 + lane * 4;
  float a0[4] = {}, a1[4] = {};
#pragma unroll 4
  for (int row = 0; row < 32; ++row) {
    float4 u4 = *(const float4*)&up[row * 256];
    int d = w * 32 + row, pd = d + (d >> 6);
    float e0 = ew0_s[pd], e1 = ew1_s[pd], mv = mv_s[pd];
#pragma unroll
    for (int j = 0; j < 4; ++j) {
      float u = j == 0 ? u4.x : j == 1 ? u4.y : j == 2 ? u4.z : u4.w;
      a0[j] = fmaf(mv, __builtin_amdgcn_rcpf(fmaf(u, e0, 1.0f)), a0[j]);
      a1[j] = fmaf(mv, __builtin_amdgcn_rcpf(fmaf(u, e1, 1.0f)), a1[j]);
    }
  }
  *(float4*)&part[w * 2 + 0][lane * 4] = make_float4(a0[0], a0[1], a0[2], a0[3]);
  *(float4*)&part[w * 2 + 1][lane * 4] = make_float4(a1[0], a1[1], a1[2], a1[3]);
  __syncthreads();

  // ---- phase 2: 16-way reduce + softmax (threads 0-511; t=tid>>8) ----
  int t = tid >> 8, col = tid & 255;
  float x = 0.f, p = 0.f, m, s;
  if (tid < 512) {
#pragma unroll
    for (int ww = 0; ww < 16; ++ww) x += part[ww * 2 + t][col];
    m = x;
#pragma unroll
    for (int off = 32; off; off >>= 1) m = fmaxf(m, __shfl_xor(m, off));
    if (lane == 0) redm[t][w & 3] = m;
  }
  __syncthreads();
  if (tid < 512) {
    m = fmaxf(fmaxf(redm[t][0], redm[t][1]), fmaxf(redm[t][2], redm[t][3]));
    p = __expf(x - m);
    s = p;
#pragma unroll
    for (int off = 32; off; off >>= 1) s += __shfl_xor(s, off);
    if (lane == 0) reds[t][w & 3] = s;
  }
  __syncthreads();
  if (tid < 512) {
    s = reds[t][0] + reds[t][1] + reds[t][2] + reds[t][3];
    float a = p * __builtin_amdgcn_rcpf(s);
    att2[col * 2 + t] = a;
    out_attn[(size_t)(b * TD_ + t0 + t) * TE_ + col] = a;
  }
  __syncthreads();

  // ---- phase 3: context; thread owns (d = tid&511, e-half = tid>>9),
  //      accumulates BOTH t rows over its 128-e half; LDS combine. ----
  int d = tid & 511, half = tid >> 9;
  const float* enc_b = enc + (size_t)b * TE_ * DE_ + (size_t)half * 128 * DE_;
  float c0 = 0.f, c1 = 0.f;
#pragma unroll 4
  for (int ee = 0; ee < 128; ++ee) {
    float2 av = *(const float2*)&att2[(half * 128 + ee) * 2];
    float xv = enc_b[(size_t)ee * DE_ + d];
    c0 = fmaf(av.x, xv, c0);
    c1 = fmaf(av.y, xv, c1);
  }
  ctxp[half][0][d] = c0;
  ctxp[half][1][d] = c1;
  __syncthreads();
  int tt = tid >> 9, dd = tid & 511;
  out_ctx[(size_t)(b * TD_ + t0 + tt) * DE_ + dd] =
      ctxp[0][tt][dd] + ctxp[1][tt][dd];
}

extern "C" void kernel_launch(void* const* d_in, const int* in_sizes, int n_in,
                              void* d_out, int out_size, void* d_ws, size_t ws_size,
                              hipStream_t stream) {
  const float* enc = (const float*)d_in[0];
  const float* dec = (const float*)d_in[1];
  const float* Ua  = (const float*)d_in[2];
  const float* Wa  = (const float*)d_in[3];
  const float* Va  = (const float*)d_in[4];

  float* out_ctx  = (float*)d_out;                     // [B,TD,DE]
  float* out_attn = out_ctx + (size_t)B_ * TD_ * DE_;  // [B,TD,TE]

  char* wsp = (char*)d_ws;
  float* EuT = (float*)wsp;             wsp += (size_t)B_ * DE_ * TE_ * 4;  // [B][512 d][256 e]
  float* Ewm = (float*)wsp;             wsp += (size_t)B_ * TD_ * DE_ * 4;  // [B*256 t][512 d]

  gemm_conv<<<dim3(256, 1, 2), 256, 0, stream>>>(enc, dec, Ua, Wa, EuT, Ewm);
  fused_attn<<<512, 1024, 0, stream>>>(enc, EuT, Ewm, Va, out_ctx, out_attn);
}